// Round 2
// baseline (518.000 us; speedup 1.0000x reference)
//
#include <hip/hip_runtime.h>

// x: (B, N+1, D) fp32, significance: (B, N) fp32, keep_tokens K=1024
constexpr int B     = 32;
constexpr int NTOK  = 4096;
constexpr int D     = 768;
constexpr int K     = 1024;
constexpr int D4    = D / 4;       // 192 float4 per row
constexpr int NROW  = NTOK + 1;    // 4097 input rows per batch
constexpr int OROWS = K + 1;       // 1025 output rows per batch
constexpr int GBLK  = 6150;        // gather blocks: 32*1025*192 / (256*4)
constexpr int GSTRIDE = GBLK * 256; // 1,574,400 float4 per sweep

typedef float vfloat4 __attribute__((ext_vector_type(4)));

// Map float bits to unsigned so unsigned compare == float compare.
__device__ __forceinline__ unsigned monotone_u32(float f) {
  unsigned u = __float_as_uint(f);
  return (u & 0x80000000u) ? ~u : (u | 0x80000000u);
}

// key = (~monotone(v) << 32) | token_idx
// ascending key order == descending value, ties -> smaller index (jax semantics).
__device__ __forceinline__ unsigned long long mkkey(float v, unsigned gidx) {
  return ((unsigned long long)(~monotone_u32(v)) << 32) | gidx;
}

// Compare-exchange via wave shuffle (partner thread = t ^ j, j <= 32).
__device__ __forceinline__ void ce_shfl(unsigned long long& key, int e, int j, int k) {
  unsigned long long pk = __shfl_xor(key, j);
  bool keepMin = (((e & j) == 0) == ((e & k) == 0));
  key = (keepMin == (key < pk)) ? key : pk;
}

// Compare-exchange between two registers of the same thread (a = lower wire).
__device__ __forceinline__ void ce_reg(unsigned long long& a, unsigned long long& b, bool up) {
  unsigned long long lo = (a < b) ? a : b;
  unsigned long long hi = (a < b) ? b : a;
  a = up ? lo : hi;
  b = up ? hi : lo;
}

// Compare-exchange via LDS exchange buffer (partner thread in other wave).
// Canonical data stays in registers; LDS is a scratch mailbox.
__device__ __forceinline__ void ce_lds(unsigned long long* lds, unsigned long long key[4],
                                       int t, int j, int k) {
  __syncthreads();                       // WAR: prior step's reads must finish
  #pragma unroll
  for (int m = 0; m < 4; ++m) lds[t + m * 1024] = key[m];
  __syncthreads();
  #pragma unroll
  for (int m = 0; m < 4; ++m) {
    int e = t + m * 1024;
    unsigned long long pk = lds[e ^ j];
    bool keepMin = (((e & j) == 0) == ((e & k) == 0));
    key[m] = (keepMin == (key[m] < pk)) ? key[m] : pk;
  }
}

// Per-batch full 4096-key bitonic sort, register-tiled:
//   j <= 32        -> __shfl_xor within wave (no LDS, no barrier)  [57 steps]
//   j in {1024,2048}-> intra-thread register CE                     [3 steps]
//   j in {64..512} -> LDS exchange (2 barriers each)                [18 steps]
// 32 blocks x 1024 threads, 32 KB LDS.
__global__ __launch_bounds__(1024)
void topk_sort(const float* __restrict__ sig, int* __restrict__ idx) {
  __shared__ unsigned long long lds[NTOK];
  const int b = blockIdx.x, t = threadIdx.x;
  const float* s = sig + (size_t)b * NTOK;

  unsigned long long key[4];
  #pragma unroll
  for (int m = 0; m < 4; ++m) {
    int e = t + m * 1024;
    key[m] = mkkey(s[e], e);
  }

  // Stages k = 2..64: every step has j <= 32 -> pure shuffles.
  #pragma unroll
  for (int k = 2; k <= 64; k <<= 1)
    for (int j = k >> 1; j > 0; j >>= 1) {
      #pragma unroll
      for (int m = 0; m < 4; ++m) ce_shfl(key[m], t + m * 1024, j, k);
    }

  // Stages k = 128..512: LDS steps (j >= 64) then shuffle steps.
  for (int k = 128; k <= 512; k <<= 1) {
    for (int j = k >> 1; j >= 64; j >>= 1) ce_lds(lds, key, t, j, k);
    for (int j = 32; j > 0; j >>= 1) {
      #pragma unroll
      for (int m = 0; m < 4; ++m) ce_shfl(key[m], t + m * 1024, j, k);
    }
  }

  // Stage k = 1024.
  for (int j = 512; j >= 64; j >>= 1) ce_lds(lds, key, t, j, 1024);
  for (int j = 32; j > 0; j >>= 1) {
    #pragma unroll
    for (int m = 0; m < 4; ++m) ce_shfl(key[m], t + m * 1024, j, 1024);
  }

  // Stage k = 2048: j=1024 is intra-thread (m0<->m1 up, m2<->m3 down).
  ce_reg(key[0], key[1], true);
  ce_reg(key[2], key[3], false);
  for (int j = 512; j >= 64; j >>= 1) ce_lds(lds, key, t, j, 2048);
  for (int j = 32; j > 0; j >>= 1) {
    #pragma unroll
    for (int m = 0; m < 4; ++m) ce_shfl(key[m], t + m * 1024, j, 2048);
  }

  // Stage k = 4096 (all ascending): j=2048 (m0<->m2, m1<->m3), j=1024 intra.
  ce_reg(key[0], key[2], true);
  ce_reg(key[1], key[3], true);
  ce_reg(key[0], key[1], true);
  ce_reg(key[2], key[3], true);
  for (int j = 512; j >= 64; j >>= 1) ce_lds(lds, key, t, j, 4096);
  for (int j = 32; j > 0; j >>= 1) {
    #pragma unroll
    for (int m = 0; m < 4; ++m) ce_shfl(key[m], t + m * 1024, j, 4096);
  }

  // Fully sorted ascending: thread t's m=0 register holds rank-t key.
  idx[b * K + t] = (int)(unsigned)(key[0] & 0xffffffffu);
}

// Gather: flat index space over output float4s, 4 coalesced sweeps per thread.
// 6150 blocks x 256 threads x 4 float4 = 32*1025*192 exactly.
__global__ __launch_bounds__(256)
void gather_kernel(const vfloat4* __restrict__ x, const int* __restrict__ idx,
                   vfloat4* __restrict__ out) {
  const int tid = blockIdx.x * 256 + threadIdx.x;

  size_t src[4];
  int    f[4];
  #pragma unroll
  for (int s = 0; s < 4; ++s) {
    f[s] = tid + s * GSTRIDE;            // < 6,297,600
    int row = f[s] / D4;                 // output row
    int c   = f[s] - row * D4;
    int bb  = row / OROWS;
    int r   = row - bb * OROWS;
    int src_row = 0;
    if (r != 0) src_row = 1 + idx[bb * K + r - 1];
    src[s] = ((size_t)bb * NROW + src_row) * D4 + c;
  }

  vfloat4 v[4];
  #pragma unroll
  for (int s = 0; s < 4; ++s) v[s] = x[src[s]];
  #pragma unroll
  for (int s = 0; s < 4; ++s) __builtin_nontemporal_store(v[s], &out[f[s]]);
}

extern "C" void kernel_launch(void* const* d_in, const int* in_sizes, int n_in,
                              void* d_out, int out_size, void* d_ws, size_t ws_size,
                              hipStream_t stream) {
  const float* x   = (const float*)d_in[0];
  const float* sig = (const float*)d_in[1];
  float* out = (float*)d_out;

  int* idx = (int*)d_ws;   // 32*1024*4 = 128 KB of workspace

  topk_sort   <<<B,    1024, 0, stream>>>(sig, idx);
  gather_kernel<<<GBLK, 256, 0, stream>>>((const vfloat4*)x, idx, (vfloat4*)out);
}